// Round 10
// baseline (202.369 us; speedup 1.0000x reference)
//
#include <hip/hip_runtime.h>
#include <math.h>

#define TT 4
#define HH 192
#define WW 192
#define SS 300
#define SP 320              // padded superpixel count (pad masked -inf)
#define HW (HH*WW)
#define PD 3
#define HSZ 22
#define NHP 484             // 22*22 halo pixels
#define NG 1936             // 16B granules per chunk buffer (4 planes x 484)
#define LOG2E 1.44269504088896340736f
#define MOFF 16384          // float index of M table [T][HW]
#define ZOFF (MOFF + TT*HW) // float index of iZ table [T][HW]

typedef _Float16 h8 __attribute__((ext_vector_type(8)));
typedef float f4 __attribute__((ext_vector_type(4)));

// ---------- ws layout (floats) ----------
// [0, 3600)    sums [T][S][3]
// [3600, 4800) cnts [T][S]
// [4800, 9920) means float4 [T][SP]: ((20/ln2)m, w = (-10/ln2)|m|^2 | -inf absent)
// [MOFF ...)   per-pixel max logit M (f32), then iZ = 1/Z (f32)

__global__ void k_zero(float* ws) {
    int i = blockIdx.x * 256 + threadIdx.x;
    if (i < TT * SS * 4) ws[i] = 0.f;
}

// LDS-staged superpixel accumulation: 16 segments x 2304 px per frame
__launch_bounds__(256)
__global__ void k_accum(const float* __restrict__ x, const int* __restrict__ spix,
                        float* __restrict__ ws) {
    __shared__ float ls[SS * 4];
    const int tid = threadIdx.x;
    const int t = blockIdx.y, seg = blockIdx.x;
    for (int i = tid; i < SS * 4; i += 256) ls[i] = 0.f;
    __syncthreads();
#pragma unroll
    for (int it = 0; it < 9; it++) {
        int px = seg * 2304 + it * 256 + tid;
        int s = spix[t * HW + px];
        atomicAdd(&ls[s * 4 + 0], x[(t * 3 + 0) * HW + px]);
        atomicAdd(&ls[s * 4 + 1], x[(t * 3 + 1) * HW + px]);
        atomicAdd(&ls[s * 4 + 2], x[(t * 3 + 2) * HW + px]);
        atomicAdd(&ls[s * 4 + 3], 1.f);
    }
    __syncthreads();
    for (int i = tid; i < SS * 4; i += 256) {
        float v = ls[i];
        if (v != 0.f) {
            int s = i >> 2, c = i & 3;
            if (c < 3) atomicAdd(&ws[(t * SS + s) * 3 + c], v);
            else       atomicAdd(&ws[3600 + t * SS + s], v);
        }
    }
}

__global__ void k_means(float* __restrict__ ws) {
    int i = blockIdx.x * 256 + threadIdx.x;
    if (i >= TT * SP) return;
    int t = i / SP, s = i - t * SP;
    const float* sums = ws;
    const float* cnts = ws + TT * SS * 3;
    float4* m4 = (float4*)(ws + 4800);
    float4 m;
    if (s < SS) {
        float c = cnts[t * SS + s];
        float inv = 1.f / fmaxf(c, 1.f);
        float mx = sums[(t * SS + s) * 3 + 0] * inv;
        float my = sums[(t * SS + s) * 3 + 1] * inv;
        float mz = sums[(t * SS + s) * 3 + 2] * inv;
        m.x = 20.f * LOG2E * mx; m.y = 20.f * LOG2E * my; m.z = 20.f * LOG2E * mz;
        m.w = (c > 0.f) ? (-10.f * LOG2E * (mx * mx + my * my + mz * mz)) : -INFINITY;
    } else {
        m.x = 0.f; m.y = 0.f; m.z = 0.f; m.w = -INFINITY;
    }
    m4[t * SP + s] = m;
}

// ---- per-pixel max logit M and iZ, 2 px/thread ----
__launch_bounds__(256)
__global__ void k_prep(const float* __restrict__ x, float* __restrict__ ws) {
    __shared__ float4 sm[SP];
    const int tid = threadIdx.x;
    const int t = blockIdx.y;
    const int p0 = blockIdx.x * 512 + tid;
    const int p1 = p0 + 256;
    const float4* m4 = (const float4*)(ws + 4800) + t * SP;
    for (int i = tid; i < SP; i += 256) sm[i] = m4[i];
    __syncthreads();
    const float f0x = x[(t * 3 + 0) * HW + p0], f0y = x[(t * 3 + 1) * HW + p0], f0z = x[(t * 3 + 2) * HW + p0];
    const float f1x = x[(t * 3 + 0) * HW + p1], f1y = x[(t * 3 + 1) * HW + p1], f1z = x[(t * 3 + 2) * HW + p1];

    float M0 = -INFINITY, M1 = -INFINITY;
#pragma unroll 4
    for (int s = 0; s < SP; s++) {
        float4 a = sm[s];
        M0 = fmaxf(M0, fmaf(f0x, a.x, fmaf(f0y, a.y, fmaf(f0z, a.z, a.w))));
        M1 = fmaxf(M1, fmaf(f1x, a.x, fmaf(f1y, a.y, fmaf(f1z, a.z, a.w))));
    }
    float Z0 = 0.f, Z1 = 0.f;
#pragma unroll 4
    for (int s = 0; s < SP; s++) {
        float4 a = sm[s];
        Z0 += exp2f(fmaf(f0x, a.x, fmaf(f0y, a.y, fmaf(f0z, a.z, a.w))) - M0);
        Z1 += exp2f(fmaf(f1x, a.x, fmaf(f1y, a.y, fmaf(f1z, a.z, a.w))) - M1);
    }
    ws[MOFF + t * HW + p0] = M0;
    ws[MOFF + t * HW + p1] = M1;
    ws[ZOFF + t * HW + p0] = 1.f / Z0;
    ws[ZOFF + t * HW + p1] = 1.f / Z1;
}

#define REP49(M) M(0)M(1)M(2)M(3)M(4)M(5)M(6)M(7)M(8)M(9)M(10)M(11)M(12)M(13) \
    M(14)M(15)M(16)M(17)M(18)M(19)M(20)M(21)M(22)M(23)M(24)M(25)M(26)M(27) \
    M(28)M(29)M(30)M(31)M(32)M(33)M(34)M(35)M(36)M(37)M(38)M(39)M(40)M(41) \
    M(42)M(43)M(44)M(45)M(46)M(47)M(48)

#define QOFF(k) (((k) / 7 - PD) * HSZ + ((k) % 7 - PD))

// ================= fused: E (in-LDS) + MFMA attn + norm + linear =================
// 16x16 tile, 1024 threads (16 waves), 1 p-row per wave -> 14 f4 accs (56 regs).
// E chunk = 32 s (4 planes of 8) in LDS, plane-major granules (jd*484+px),
// double-buffered. phaseB: 2 threads per halo px (16 s each).
// attn gathered via f32 LDS overlay (stride 51) aliasing ebuf; epilogue 1 thread/px.

__launch_bounds__(1024, 4)
__global__ void k_main(const float* __restrict__ x, const float* __restrict__ Wlin,
                       const float* __restrict__ blin, const float* __restrict__ ws,
                       float* __restrict__ out) {
    __shared__ __align__(16) char ebuf[2][NG * 16];   // 61952 B (attn overlay reuses this)
    __shared__ float4 sfh[NHP];                       // xyz = feature, w = iZ (0 if OOB)
    __shared__ float  sW[441];

    const int tid = threadIdx.x;
    const int wid = tid >> 6, lane = tid & 63;
    const int pxc = lane & 15, kg = lane >> 4;        // MFMA fragment coords
    const int t = blockIdx.z;
    const int gx0 = blockIdx.x * 16 - PD, gy0 = blockIdx.y * 16 - PD;
    const float4* m4 = (const float4*)(ws + 4800) + t * SP;

    for (int i = tid; i < 441; i += 1024) sW[i] = Wlin[i];

    // ---- per-thread halo-pixel state: threads 0..483 = half 0 (jd 0,1),
    //      484..967 = half 1 (jd 2,3); same hp in both halves ----
    const int half = (tid >= NHP) ? 1 : 0;
    const int hp = tid - half * NHP;
    float fx = 0.f, fy = 0.f, fz = 0.f, M = INFINITY;
    if (tid < 2 * NHP) {
        int hy = hp / HSZ, hx = hp - hy * HSZ;
        int gy = gy0 + hy, gx = gx0 + hx;
        if (gy >= 0 && gy < HH && gx >= 0 && gx < WW) {
            int p = gy * WW + gx;
            fx = x[(t * 3 + 0) * HW + p];
            fy = x[(t * 3 + 1) * HW + p];
            fz = x[(t * 3 + 2) * HW + p];
            M  = ws[MOFF + t * HW + p];
            if (half == 0) sfh[hp] = make_float4(fx, fy, fz, ws[ZOFF + t * HW + p]);
        } else if (half == 0) {
            sfh[hp] = make_float4(0.f, 0.f, 0.f, 0.f);
        }
    }

    // phase B: E values for chunk cc -> buffer bb (OOB px: M=+inf -> E=0)
#define PHASEB(cc, bb) if (tid < 2 * NHP) { \
        char* dst = ebuf[bb]; \
        _Pragma("unroll") \
        for (int j2 = 0; j2 < 2; j2++) { \
            int jd = 2 * half + j2; \
            h8 v; \
            _Pragma("unroll") \
            for (int e = 0; e < 4; e++) { \
                float4 ma = m4[(cc) * 32 + jd * 8 + 2 * e]; \
                float4 mb = m4[(cc) * 32 + jd * 8 + 2 * e + 1]; \
                float E0 = exp2f(fmaf(fx, ma.x, fmaf(fy, ma.y, fmaf(fz, ma.z, ma.w))) - M); \
                float E1 = exp2f(fmaf(fx, mb.x, fmaf(fy, mb.y, fmaf(fz, mb.z, mb.w))) - M); \
                auto pr = __builtin_amdgcn_cvt_pkrtz(E0, E1); \
                v[2 * e] = (_Float16)pr.x; v[2 * e + 1] = (_Float16)pr.y; \
            } \
            *(h8*)(dst + (jd * NHP + hp) * 16) = v; \
        } }

    // ---- MFMA setup: wave owns p-row r = wid ----
    const int r = wid;
    const int gA0 = kg * NHP + (r + PD) * HSZ + PD + pxc;           // A row r
    const int bcol2 = (16 + pxc > 21) ? 21 : 16 + pxc;              // clamped tile2 col
    const int gB1 = kg * NHP + r * HSZ + pxc;                       // + d*HSZ
    const int gB2 = kg * NHP + r * HSZ + bcol2;                     // + d*HSZ

    f4 zero4 = {0.f, 0.f, 0.f, 0.f};
    f4 aP[7], aQ[7];                 // (A,B1[d]) (A,B2[d])
#pragma unroll
    for (int d = 0; d < 7; d++) { aP[d] = zero4; aQ[d] = zero4; }

    PHASEB(0, 0)

#pragma unroll 1
    for (int c = 0; c < 10; c++) {
        __syncthreads();               // phaseB(c) visible; MFMA(c-1) reads done
        if (c < 9) { PHASEB(c + 1, (c + 1) & 1) }
        const char* pb = ebuf[c & 1];
        h8 A0 = *(const h8*)(pb + gA0 * 16);
#pragma unroll
        for (int d = 0; d < 7; d++) {
            h8 n1 = *(const h8*)(pb + (gB1 + d * HSZ) * 16);
            h8 n2 = *(const h8*)(pb + (gB2 + d * HSZ) * 16);
            aP[d] = __builtin_amdgcn_mfma_f32_16x16x32_f16(A0, n1, aP[d], 0, 0, 0);
            aQ[d] = __builtin_amdgcn_mfma_f32_16x16x32_f16(A0, n2, aQ[d], 0, 0, 0);
        }
    }
    __syncthreads();                   // last MFMA reads done; ebuf reusable

    // ---- band write-out: D[i = 4*kg+reg, j = pxc] -> attn[px][k] (each slot once) ----
    float* attn = (float*)ebuf;        // [256 px][stride 51] f32, 52.2 KB < 62 KB
#pragma unroll
    for (int d = 0; d < 7; d++) {
#pragma unroll
        for (int reg = 0; reg < 4; reg++) {
            int i = 4 * kg + reg;
            int u1 = pxc - i;          // tile1: dx+3 = j-i
            int u2 = u1 + 16;          // tile2: dx+3 = 16+j-i
            if ((unsigned)u1 <= 6u) attn[(r * 16 + i) * 51 + d * 7 + u1] = aP[d][reg];
            if ((unsigned)u2 <= 6u) attn[(r * 16 + i) * 51 + d * 7 + u2] = aQ[d][reg];
        }
    }
    __syncthreads();

    // ---- normalize (eps+max semantics) + linear epilogue (1 thread / pixel) ----
    if (tid < 256) {
        const int rr = tid >> 4, cq = tid & 15;
        const int own = (rr + PD) * HSZ + (cq + PD);
        const float* ap = attn + tid * 51;
        float mx = 0.f;
#define PK1(k) mx = fmaxf(mx, ap[k] * sfh[own + QOFF(k)].w);
        REP49(PK1)
#undef PK1
        const float iZp = sfh[own].w;
        const float inv = 1.f / (1e-5f / iZp + mx);

        float o0 = blin[0], o1 = blin[1], o2 = blin[2];
#define PK2(k) { float4 f = sfh[own + QOFF(k)]; \
        float rwk = ap[k] * f.w * inv; \
        o0 += rwk * (sW[k] * f.x + sW[49 + (k)] * f.y + sW[98 + (k)] * f.z); \
        o1 += rwk * (sW[147 + (k)] * f.x + sW[196 + (k)] * f.y + sW[245 + (k)] * f.z); \
        o2 += rwk * (sW[294 + (k)] * f.x + sW[343 + (k)] * f.y + sW[392 + (k)] * f.z); }
        REP49(PK2)
#undef PK2

        int p = (gy0 + PD + rr) * WW + gx0 + PD + cq;
        out[(t * 3 + 0) * HW + p] = o0;
        out[(t * 3 + 1) * HW + p] = o1;
        out[(t * 3 + 2) * HW + p] = o2;
    }
}

extern "C" void kernel_launch(void* const* d_in, const int* in_sizes, int n_in,
                              void* d_out, int out_size, void* d_ws, size_t ws_size,
                              hipStream_t stream) {
    (void)in_sizes; (void)n_in; (void)out_size; (void)ws_size;
    const float* x    = (const float*)d_in[0];
    const int*   spix = (const int*)d_in[1];
    const float* Wlin = (const float*)d_in[2];
    const float* blin = (const float*)d_in[3];
    float* out = (float*)d_out;
    float* ws  = (float*)d_ws;

    hipLaunchKernelGGL(k_zero,  dim3(19), dim3(256), 0, stream, ws);
    hipLaunchKernelGGL(k_accum, dim3(16, TT), dim3(256), 0, stream, x, spix, ws);
    hipLaunchKernelGGL(k_means, dim3((TT * SP + 255) / 256), dim3(256), 0, stream, ws);
    hipLaunchKernelGGL(k_prep,  dim3(HW / 512, TT), dim3(256), 0, stream, x, ws);
    hipLaunchKernelGGL(k_main,  dim3(WW / 16, HH / 16, TT), dim3(1024), 0, stream,
                       x, Wlin, blin, ws, out);
}